// Round 11
// baseline (2578.821 us; speedup 1.0000x reference)
//
#include <hip/hip_runtime.h>
#include <hip/hip_bf16.h>

typedef __attribute__((ext_vector_type(8))) short bf16x8_t;
typedef __attribute__((ext_vector_type(4))) float f32x4_t;
typedef __attribute__((ext_vector_type(4))) unsigned int u32x4_t;

#define XP_BYTES 55115776u   // 4*16*58*58*128*2
#define WT_BYTES 2359296u    // 144 units * 256 oc * 32 k * 2B (frag-native)

typedef __attribute__((address_space(1))) const unsigned int ga_u32_t;
typedef __attribute__((address_space(3))) unsigned int lds_u32_t;

__device__ __forceinline__ void g2l16(const void* g, void* l) {
  __builtin_amdgcn_global_load_lds((ga_u32_t*)g, (lds_u32_t*)l, 16, 0, 0);
}

// ---------------------------------------------------------------------------
// prep_x: x (16,256,56,56) f32 -> xp (4,16,58,58,128) bf16, inner = hl*64+c.
// Writes its own zero borders (rows 0/57, cols 0/57) -> no xp memset needed.
// ---------------------------------------------------------------------------
__global__ __launch_bounds__(256) void prep_x(const float* __restrict__ x,
                                              __hip_bfloat16* __restrict__ xp) {
  __shared__ float ls[64 * 57];
  int blk = blockIdx.x;            // (g, b, h) : 4*16*56 = 3584
  int g = blk / 896;
  int r = blk - g * 896;
  int b = r / 56;
  int h = r - b * 56;
  int tid = threadIdx.x;
  const float* src = x + (size_t)(b * 256 + g * 64) * 3136 + h * 56;
  for (int i = tid; i < 64 * 56; i += 256) {
    int c = i / 56, w = i - c * 56;
    ls[c * 57 + w] = src[(size_t)c * 3136 + w];
  }
  __syncthreads();
  __hip_bfloat16* gbbase = xp + (size_t)(g * 16 + b) * 58 * 58 * 128;
  __hip_bfloat16* dst = gbbase + ((size_t)(h + 1) * 58 + 1) * 128;
  int wp = tid >> 7;
  int inner = tid & 127;
  int hl = inner >> 6, c = inner & 63;
  for (int w0 = 0; w0 < 56; w0 += 2) {
    int w = w0 + wp;
    float v = ls[c * 57 + w];
    __hip_bfloat16 hi = __float2bfloat16(v);
    __hip_bfloat16 val = hl ? __float2bfloat16(v - __bfloat162float(hi)) : hi;
    dst[(size_t)w * 128 + inner] = val;
  }
  __hip_bfloat16 z = __float2bfloat16(0.0f);
  {
    __hip_bfloat16* rowp = gbbase + (size_t)(h + 1) * 58 * 128;
    if (tid < 128) rowp[inner] = z;              // col 0
    else           rowp[57 * 128 + inner] = z;   // col 57
  }
  if (h == 0) {
    for (int i = tid; i < 58 * 128; i += 256) gbbase[i] = z;    // row 0
  }
  if (h == 55) {
    __hip_bfloat16* r57 = gbbase + (size_t)57 * 58 * 128;
    for (int i = tid; i < 58 * 128; i += 256) r57[i] = z;       // row 57
  }
}

// ---------------------------------------------------------------------------
// prep_w: weight (256,256,3,3) f32 -> FRAG-NATIVE layout:
//   wtf[u][wq 0..3][ni 0..3][lane 0..63][8 bf16]
// u = g*36 + sgn*18 + tap*2 + cc; lane's 16B = its MFMA B-operand fragment:
// oc = wq*64 + ni*16 + (l&15), k = (l>>4)*8 + e, channel c = cc*32 + k.
// ---------------------------------------------------------------------------
__global__ __launch_bounds__(256) void prep_w(const float* __restrict__ wgt,
                                              const float* __restrict__ wsc,
                                              unsigned short* __restrict__ wtf) {
  int idx = blockIdx.x * 256 + threadIdx.x;   // 147456 = 144*4*4*64
  if (idx >= 147456) return;
  int l = idx & 63;
  int ni = (idx >> 6) & 3;
  int wq = (idx >> 8) & 3;
  int u = idx >> 10;                          // 0..143
  int g = u / 36;
  int r36 = u - g * 36;
  int sgn = (r36 >= 18) ? 1 : 0;
  int r18 = r36 - sgn * 18;
  int tap = r18 >> 1, cc = r18 & 1;
  int oc = wq * 64 + ni * 16 + (l & 15);
  float inv = 1.f / wsc[g];
  unsigned short pk[8];
#pragma unroll
  for (int e = 0; e < 8; ++e) {
    int c = cc * 32 + ((l >> 4) << 3) + e;
    float w = wgt[(size_t)oc * 2304 + (g * 64 + c) * 9 + tap] * inv;
    if (sgn) w = -w;
    float q = rintf(fminf(fmaxf(w, 0.f), 3.f));
    union { __hip_bfloat16 h; unsigned short s; } cv;
    cv.h = __float2bfloat16(q);
    pk[e] = cv.s;
  }
  u32x4_t v;
  v[0] = (unsigned)pk[0] | ((unsigned)pk[1] << 16);
  v[1] = (unsigned)pk[2] | ((unsigned)pk[3] << 16);
  v[2] = (unsigned)pk[4] | ((unsigned)pk[5] << 16);
  v[3] = (unsigned)pk[6] | ((unsigned)pk[7] << 16);
  *(u32x4_t*)(wtf + (size_t)idx * 8) = v;
}

// ---------------------------------------------------------------------------
// Main conv. Grid 784 = 16 b x 49 aligned 64-px tiles; BM=64 px, BN=256 oc.
// 512 thr = 8 waves (2M x 4N), wave tile 32x64 -> per-wave regs ~108 (<=128,
// measured R10) -> with __launch_bounds__(512,4): 4 waves/SIMD, 2 blocks/CU
// (LDS 2 x 64KB). Double the TLP of R7 at the same per-block overhead.
// A: 4-row strip (64KB LDS), staged once per group; conflict-free XOR
//    swizzle (row stride 64 px). Barriers only at group boundaries.
// B: frag-native global->register, 2-deep set pipeline, counted VMCNT4.
// Unit order: READA (ds issue) -> VMCNT4 -> 16 MFMA -> LOADB(u+2).
// ---------------------------------------------------------------------------
#define MEMPIN asm volatile("" ::: "memory")
#define BAR __builtin_amdgcn_s_barrier()
#define VMCNT4 asm volatile("s_waitcnt vmcnt(4)" ::: "memory")
#define VMCNT0 asm volatile("s_waitcnt vmcnt(0)" ::: "memory")
#define LGKM0 asm volatile("s_waitcnt lgkmcnt(0)" ::: "memory")

__global__ __launch_bounds__(512, 4) void conv_mfma(
    const unsigned short* __restrict__ xp, const unsigned short* __restrict__ wtf,
    const float* __restrict__ wsc, const float* __restrict__ psp,
    const float* __restrict__ psn, float* __restrict__ out) {
  __shared__ char Astrip[65536];               // 4 rows x 64 px x 256B

  const int bid = blockIdx.x;
  const int wg = (bid & 7) * 98 + (bid >> 3);  // bijective XCD swizzle (784=8*98)
  const int b = wg / 49;
  const int t = wg - b * 49;                   // aligned 64-px tile
  const int r0 = (t << 6) / 56;                // top padded xp-row of strip

  const int tid = threadIdx.x;
  const int wv = tid >> 6;
  const int l = tid & 63;
  const int wr = wv >> 2, wc = wv & 3;         // 2M x 4N wave grid

  // ---- A frag pixel bases (strip-relative, 64-px row stride)
  int pxb[2];
#pragma unroll
  for (int mi = 0; mi < 2; ++mi) {
    int m = (t << 6) + wr * 32 + mi * 16 + (l & 15);
    int rv = m / 56, w = m - rv * 56;
    pxb[mi] = ((rv - r0) << 6) + w;
  }

  // ---- scalars preloaded
  float w0s = wsc[0], w1s = wsc[1], w2s = wsc[2], w3s = wsc[3];
  float p0 = psp[0], p1 = psp[1], p2 = psp[2], p3 = psp[3];
  float n0 = psn[0], n1 = psn[1], n2 = psn[2], n3 = psn[3];

  f32x4_t acc[2][4], oacc[2][4];
  const f32x4_t fz = {0.f, 0.f, 0.f, 0.f};
#pragma unroll
  for (int i = 0; i < 2; ++i)
#pragma unroll
    for (int j = 0; j < 4; ++j) { acc[i][j] = fz; oacc[i][j] = fz; }

  const char* xg = (const char*)xp;
  const char* wtb = (const char*)wtf + (wc << 12) + (l << 4);  // per-lane B base
  const unsigned a_gbbase = (unsigned)((b * 3364 + r0 * 58) * 256);

  // stage the 64KB strip for group gg: 4096 chunks = 8/thread exactly
#define STAGE_STRIP(gg)                                                        \
  {                                                                            \
    const char* s_ = xg + (unsigned)(gg)*13778944u + a_gbbase;                 \
    _Pragma("unroll")                                                          \
    for (int k_ = 0; k_ < 8; ++k_) {                                           \
      int idx_ = tid + (k_ << 9);                                              \
      int px_ = idx_ >> 4, sl_ = idx_ & 15;                                    \
      int sr_ = px_ >> 6, xc_ = px_ & 63;                                      \
      g2l16(s_ + (sr_ * 58 + xc_) * 256 +                                      \
                (((sl_ & 8) | ((sl_ & 7) ^ (xc_ & 7))) << 4),                  \
            Astrip + idx_ * 16);                                               \
    }                                                                          \
  }

#define LOADB(d0, d1, d2, d3, uu)                                              \
  {                                                                            \
    const char* p_ = wtb + (unsigned)(uu) * 16384u;                            \
    d0 = *(const bf16x8_t*)(p_);                                               \
    d1 = *(const bf16x8_t*)(p_ + 1024);                                        \
    d2 = *(const bf16x8_t*)(p_ + 2048);                                        \
    d3 = *(const bf16x8_t*)(p_ + 3072);                                        \
  }

  // A frag reads: strip row = ty, col = pxb + tx (4 ds_read_b128)
#define READA(cc_, ty_, tx_)                                                   \
  {                                                                            \
    const int kj_ = ((cc_) << 2) + (l >> 4);                                   \
    _Pragma("unroll")                                                          \
    for (int mi = 0; mi < 2; ++mi) {                                           \
      int px_ = pxb[mi] + ((ty_) << 6) + (tx_);                                \
      int base_ = (px_ << 8) + ((kj_ ^ (px_ & 7)) << 4);                       \
      ahi[mi] = *(const bf16x8_t*)(Astrip + base_);                            \
      alo[mi] = *(const bf16x8_t*)(Astrip + base_ + 128);                      \
    }                                                                          \
  }

#define MMA16(B0, B1, B2, B3)                                                  \
  __builtin_amdgcn_s_setprio(1);                                               \
  _Pragma("unroll")                                                            \
  for (int mi = 0; mi < 2; ++mi) {                                             \
    acc[mi][0] = __builtin_amdgcn_mfma_f32_16x16x32_bf16(ahi[mi], B0, acc[mi][0], 0, 0, 0); \
    acc[mi][1] = __builtin_amdgcn_mfma_f32_16x16x32_bf16(ahi[mi], B1, acc[mi][1], 0, 0, 0); \
    acc[mi][2] = __builtin_amdgcn_mfma_f32_16x16x32_bf16(ahi[mi], B2, acc[mi][2], 0, 0, 0); \
    acc[mi][3] = __builtin_amdgcn_mfma_f32_16x16x32_bf16(ahi[mi], B3, acc[mi][3], 0, 0, 0); \
    acc[mi][0] = __builtin_amdgcn_mfma_f32_16x16x32_bf16(alo[mi], B0, acc[mi][0], 0, 0, 0); \
    acc[mi][1] = __builtin_amdgcn_mfma_f32_16x16x32_bf16(alo[mi], B1, acc[mi][1], 0, 0, 0); \
    acc[mi][2] = __builtin_amdgcn_mfma_f32_16x16x32_bf16(alo[mi], B2, acc[mi][2], 0, 0, 0); \
    acc[mi][3] = __builtin_amdgcn_mfma_f32_16x16x32_bf16(alo[mi], B3, acc[mi][3], 0, 0, 0); \
  }                                                                            \
  __builtin_amdgcn_s_setprio(0);

#define QUANTIZE(gg, ss)                                                       \
  {                                                                            \
    float sw = ((gg) & 2) ? (((gg) & 1) ? w3s : w2s) : (((gg) & 1) ? w1s : w0s); \
    float sp = ((gg) & 2) ? (((gg) & 1) ? p3 : p2) : (((gg) & 1) ? p1 : p0);   \
    float sn = ((gg) & 2) ? (((gg) & 1) ? n3 : n2) : (((gg) & 1) ? n1 : n0);   \
    float sq = (ss) ? sn : sp;                                                 \
    float rs = sw / sq;                                                        \
    float sm = (ss) ? -sq : sq;                                                \
    _Pragma("unroll")                                                          \
    for (int mi = 0; mi < 2; ++mi)                                             \
      _Pragma("unroll")                                                        \
      for (int ni = 0; ni < 4; ++ni)                                           \
        _Pragma("unroll")                                                      \
        for (int j = 0; j < 4; ++j) {                                          \
          float v = acc[mi][ni][j] * rs;                                       \
          v = fminf(fmaxf(v, -128.f), 127.f);                                  \
          oacc[mi][ni][j] += sm * rintf(v);                                    \
          acc[mi][ni][j] = 0.f;                                                \
        }                                                                      \
  }

  bf16x8_t ahi[2], alo[2];
  bf16x8_t bA0, bA1, bA2, bA3, bB0, bB1, bB2, bB3;

  // ---- prologue: strip(0) [8/thread] + B(0), B(1) [8] in flight
  STAGE_STRIP(0);
  MEMPIN;
  LOADB(bA0, bA1, bA2, bA3, 0);
  LOADB(bB0, bB1, bB2, bB3, 1);
  VMCNT4;                        // strip + B(0) landed; B(1) still flying
  BAR;
  MEMPIN;

  for (int g = 0; g < 4; ++g) {
    const int ub = g * 36;
    for (int u36 = 0; u36 < 36; ++u36) {
      const int u = ub + u36;
      const int sgn = (u36 >= 18) ? 1 : 0;
      const int r18 = u36 - (sgn ? 18 : 0);
      const int tap = r18 >> 1, cc = r18 & 1;
      const int ty = tap / 3;
      const int tx = tap - ty * 3;

      READA(cc, ty, tx);         // ds_reads issue first: overlap the B wait
      if (u == 143) { VMCNT0; } else { VMCNT4; }
      if (u36 & 1) {
        MMA16(bB0, bB1, bB2, bB3);
        if (u + 2 < 144) { LOADB(bB0, bB1, bB2, bB3, u + 2); }
      } else {
        MMA16(bA0, bA1, bA2, bA3);
        if (u + 2 < 144) { LOADB(bA0, bA1, bA2, bA3, u + 2); }
      }
      if (u36 == 17) { QUANTIZE(g, 0); }
      if (u36 == 35) { QUANTIZE(g, 1); }
    }
    // ---- group boundary: republish strip for next group
    if (g < 3) {
      LGKM0;                     // strip reads data-complete
      BAR;                       // all waves done reading strip(g)
      MEMPIN;
      STAGE_STRIP(g + 1);
      VMCNT0;                    // strip (and in-flight B) landed
      BAR;
      MEMPIN;
    }
  }

  // ---- store (aligned 64-px tiles: no masking needed)
#pragma unroll
  for (int ni = 0; ni < 4; ++ni) {
    int oc = wc * 64 + ni * 16 + (l & 15);
    float* orow = out + ((size_t)(b * 256 + oc)) * 3136;
#pragma unroll
    for (int mi = 0; mi < 2; ++mi) {
      int m0 = (t << 6) + wr * 32 + mi * 16 + ((l >> 4) << 2);
#pragma unroll
      for (int j = 0; j < 4; ++j) {
        orow[m0 + j] = oacc[mi][ni][j];
      }
    }
  }
#undef STAGE_STRIP
#undef LOADB
#undef READA
#undef MMA16
#undef QUANTIZE
}

// ---------------------------------------------------------------------------
// Fallback (ws too small): direct conv with inline weight quantization.
// ---------------------------------------------------------------------------
__global__ __launch_bounds__(256) void naive_conv(
    const float* __restrict__ x, const float* __restrict__ wgt,
    const float* __restrict__ wsc, const float* __restrict__ psp,
    const float* __restrict__ psn, float* __restrict__ out) {
  int idx = blockIdx.x * 256 + threadIdx.x;
  if (idx >= 12845056) return;
  int b = idx / 802816;
  int r = idx - b * 802816;
  int oc = r / 3136;
  int hw = r - oc * 3136;
  int h = hw / 56, w = hw - (hw / 56) * 56;
  float o = 0.f;
  for (int g = 0; g < 4; ++g) {
    float sw = wsc[g];
    float inv = 1.f / sw;
    float pp = 0.f, pn = 0.f;
    for (int tap = 0; tap < 9; ++tap) {
      int y = h + tap / 3 - 1, xx = w + tap % 3 - 1;
      if (y < 0 || y > 55 || xx < 0 || xx > 55) continue;
      const float* xr = x + (size_t)(b * 256 + g * 64) * 3136 + y * 56 + xx;
      const float* wrr = wgt + (size_t)oc * 2304 + (size_t)(g * 64) * 9 + tap;
      for (int c = 0; c < 64; ++c) {
        float xv = xr[(size_t)c * 3136];
        float rv = wrr[c * 9] * inv;
        pp += xv * rintf(fminf(fmaxf(rv, 0.f), 3.f));
        pn += xv * rintf(fminf(fmaxf(-rv, 0.f), 3.f));
      }
    }
    float sp = psp[g], sn = psn[g];
    o += rintf(fminf(fmaxf(pp * (sw / sp), -128.f), 127.f)) * sp;
    o -= rintf(fminf(fmaxf(pn * (sw / sn), -128.f), 127.f)) * sn;
  }
  out[idx] = o;
}

extern "C" void kernel_launch(void* const* d_in, const int* in_sizes, int n_in,
                              void* d_out, int out_size, void* d_ws, size_t ws_size,
                              hipStream_t stream) {
  const float* x = (const float*)d_in[0];
  const float* wgt = (const float*)d_in[1];
  const float* wsc = (const float*)d_in[2];
  const float* psp = (const float*)d_in[3];
  const float* psn = (const float*)d_in[4];
  float* out = (float*)d_out;

  if (ws_size >= (size_t)XP_BYTES + (size_t)WT_BYTES) {
    unsigned short* xpw = (unsigned short*)d_ws;
    unsigned short* wtw = (unsigned short*)((char*)d_ws + XP_BYTES);
    prep_x<<<3584, 256, 0, stream>>>(x, (__hip_bfloat16*)xpw);
    prep_w<<<576, 256, 0, stream>>>(wgt, wsc, wtw);
    conv_mfma<<<784, 512, 0, stream>>>(xpw, wtw, wsc, psp, psn, out);
  } else {
    naive_conv<<<(12845056 + 255) / 256, 256, 0, stream>>>(x, wgt, wsc, psp, psn, out);
  }
}

// Round 12
// 263.540 us; speedup vs baseline: 9.7853x; 9.7853x over previous
//
#include <hip/hip_runtime.h>
#include <hip/hip_bf16.h>

typedef __attribute__((ext_vector_type(8))) short bf16x8_t;
typedef __attribute__((ext_vector_type(4))) float f32x4_t;
typedef __attribute__((ext_vector_type(16))) float f32x16_t;
typedef __attribute__((ext_vector_type(4))) unsigned int u32x4_t;

#define XP_BYTES 55115776u   // 4*16*58*58*128*2
#define WT_BYTES 2359296u    // 144 units * 256 oc * 32 k * 2B (frag-native)

typedef __attribute__((address_space(1))) const unsigned int ga_u32_t;
typedef __attribute__((address_space(3))) unsigned int lds_u32_t;

__device__ __forceinline__ void g2l16(const void* g, void* l) {
  __builtin_amdgcn_global_load_lds((ga_u32_t*)g, (lds_u32_t*)l, 16, 0, 0);
}

// ---------------------------------------------------------------------------
// prep_x: x (16,256,56,56) f32 -> xp (4,16,58,58,128) bf16, inner = hl*64+c.
// Writes its own zero borders (rows 0/57, cols 0/57) -> no xp memset needed.
// ---------------------------------------------------------------------------
__global__ __launch_bounds__(256) void prep_x(const float* __restrict__ x,
                                              __hip_bfloat16* __restrict__ xp) {
  __shared__ float ls[64 * 57];
  int blk = blockIdx.x;            // (g, b, h) : 4*16*56 = 3584
  int g = blk / 896;
  int r = blk - g * 896;
  int b = r / 56;
  int h = r - b * 56;
  int tid = threadIdx.x;
  const float* src = x + (size_t)(b * 256 + g * 64) * 3136 + h * 56;
  for (int i = tid; i < 64 * 56; i += 256) {
    int c = i / 56, w = i - c * 56;
    ls[c * 57 + w] = src[(size_t)c * 3136 + w];
  }
  __syncthreads();
  __hip_bfloat16* gbbase = xp + (size_t)(g * 16 + b) * 58 * 58 * 128;
  __hip_bfloat16* dst = gbbase + ((size_t)(h + 1) * 58 + 1) * 128;
  int wp = tid >> 7;
  int inner = tid & 127;
  int hl = inner >> 6, c = inner & 63;
  for (int w0 = 0; w0 < 56; w0 += 2) {
    int w = w0 + wp;
    float v = ls[c * 57 + w];
    __hip_bfloat16 hi = __float2bfloat16(v);
    __hip_bfloat16 val = hl ? __float2bfloat16(v - __bfloat162float(hi)) : hi;
    dst[(size_t)w * 128 + inner] = val;
  }
  __hip_bfloat16 z = __float2bfloat16(0.0f);
  {
    __hip_bfloat16* rowp = gbbase + (size_t)(h + 1) * 58 * 128;
    if (tid < 128) rowp[inner] = z;              // col 0
    else           rowp[57 * 128 + inner] = z;   // col 57
  }
  if (h == 0) {
    for (int i = tid; i < 58 * 128; i += 256) gbbase[i] = z;    // row 0
  }
  if (h == 55) {
    __hip_bfloat16* r57 = gbbase + (size_t)57 * 58 * 128;
    for (int i = tid; i < 58 * 128; i += 256) r57[i] = z;       // row 57
  }
}

// ---------------------------------------------------------------------------
// prep_w for 32x32x16 MFMA. FRAG-NATIVE layout:
//   wtf[u][wq 0..3][part 0..3][lane 0..63][8 bf16],  part = nj*2 + kseg
// u = g*36 + sgn*18 + tap*2 + cc. Lane's 16B = its 32x32x16 B-operand frag:
//   oc = wq*64 + nj*32 + (l&31),  channel c = cc*32 + kseg*16 + (l>>5)*8 + e.
// Quant levels 0..3 exact in bf16; identical for hl (dedup'd).
// ---------------------------------------------------------------------------
__global__ __launch_bounds__(256) void prep_w(const float* __restrict__ wgt,
                                              const float* __restrict__ wsc,
                                              unsigned short* __restrict__ wtf) {
  int idx = blockIdx.x * 256 + threadIdx.x;   // 147456 = 144*4*4*64
  if (idx >= 147456) return;
  int l = idx & 63;
  int part = (idx >> 6) & 3;
  int wq = (idx >> 8) & 3;
  int u = idx >> 10;                          // 0..143
  int g = u / 36;
  int r36 = u - g * 36;
  int sgn = (r36 >= 18) ? 1 : 0;
  int r18 = r36 - sgn * 18;
  int tap = r18 >> 1, cc = r18 & 1;
  int nj = part >> 1, kseg = part & 1;
  int oc = wq * 64 + nj * 32 + (l & 31);
  float inv = 1.f / wsc[g];
  unsigned short pk[8];
#pragma unroll
  for (int e = 0; e < 8; ++e) {
    int c = cc * 32 + kseg * 16 + ((l >> 5) << 3) + e;
    float w = wgt[(size_t)oc * 2304 + (g * 64 + c) * 9 + tap] * inv;
    if (sgn) w = -w;
    float q = rintf(fminf(fmaxf(w, 0.f), 3.f));
    union { __hip_bfloat16 h; unsigned short s; } cv;
    cv.h = __float2bfloat16(q);
    pk[e] = cv.s;
  }
  u32x4_t v;
  v[0] = (unsigned)pk[0] | ((unsigned)pk[1] << 16);
  v[1] = (unsigned)pk[2] | ((unsigned)pk[3] << 16);
  v[2] = (unsigned)pk[4] | ((unsigned)pk[5] << 16);
  v[3] = (unsigned)pk[6] | ((unsigned)pk[7] << 16);
  *(u32x4_t*)(wtf + (size_t)idx * 8) = v;
}

// ---------------------------------------------------------------------------
// Main conv — exact R7 skeleton (241us measured), MFMA switched to 32x32x16.
// Grid 784 = 16 b x 49 aligned 64-px tiles. BM=64 px, BN=256 oc. 256 thr =
// 4 waves (N quarters), wave tile 64x64 as 2x2 of 32x32, 2 blocks/CU.
// A: 4-row strip (64KB LDS), staged once per group; taps = LDS offsets;
//    XOR slot swizzle: per b128 read, 32 rows x 2 kg hit each bank-quad
//    exactly 8x16B = minimal 8 cycles (conflict-optimal).
// B: frag-native global->register, 2-deep set pipeline, counted VMCNT4.
// Unit (g,sgn,tap,cc): 8 ds_read_b128 + 16 MFMA 32x32x16 (hl-paired B reuse).
// ---------------------------------------------------------------------------
#define MEMPIN asm volatile("" ::: "memory")
#define BAR __builtin_amdgcn_s_barrier()
#define VMCNT4 asm volatile("s_waitcnt vmcnt(4)" ::: "memory")
#define VMCNT0 asm volatile("s_waitcnt vmcnt(0)" ::: "memory")

__global__ __launch_bounds__(256, 2) void conv_mfma(
    const unsigned short* __restrict__ xp, const unsigned short* __restrict__ wtf,
    const float* __restrict__ wsc, const float* __restrict__ psp,
    const float* __restrict__ psn, float* __restrict__ out) {
  __shared__ char Astrip[65536];               // 4 rows x 64 px x 256B

  const int bid = blockIdx.x;
  const int wg = (bid & 7) * 98 + (bid >> 3);  // bijective XCD swizzle (784=8*98)
  const int b = wg / 49;
  const int t = wg - b * 49;
  const int r0 = (t << 6) / 56;                // top padded xp-row of strip

  const int tid = threadIdx.x;
  const int wv = tid >> 6;                     // N quarter 0..3
  const int l = tid & 63;

  // ---- A frag pixel bases: row = t*64 + mi*32 + (l&31)
  int pxb[2];
#pragma unroll
  for (int mi = 0; mi < 2; ++mi) {
    int m = (t << 6) + mi * 32 + (l & 31);
    int rv = m / 56, w = m - rv * 56;
    pxb[mi] = ((rv - r0) << 6) + w;
  }

  // ---- scalars preloaded
  float w0s = wsc[0], w1s = wsc[1], w2s = wsc[2], w3s = wsc[3];
  float p0 = psp[0], p1 = psp[1], p2 = psp[2], p3 = psp[3];
  float n0 = psn[0], n1 = psn[1], n2 = psn[2], n3 = psn[3];

  f32x16_t acc[2][2], oacc[2][2];
#pragma unroll
  for (int i = 0; i < 2; ++i)
#pragma unroll
    for (int j = 0; j < 2; ++j)
#pragma unroll
      for (int e = 0; e < 16; ++e) { acc[i][j][e] = 0.f; oacc[i][j][e] = 0.f; }

  const char* xg = (const char*)xp;
  const char* wtb = (const char*)wtf + (wv << 12) + (l << 4);  // per-lane B base
  const unsigned a_gbbase = (unsigned)((b * 3364 + r0 * 58) * 256);

  // stage the 64KB strip for group gg (16 loads/thread)
#define STAGE_STRIP(gg)                                                        \
  {                                                                            \
    const char* s_ = xg + (unsigned)(gg)*13778944u + a_gbbase;                 \
    _Pragma("unroll")                                                          \
    for (int k_ = 0; k_ < 16; ++k_) {                                          \
      int idx_ = tid + (k_ << 8);                                              \
      int px_ = idx_ >> 4, sl_ = idx_ & 15;                                    \
      int sr_ = px_ >> 6, xc_ = px_ & 63;                                      \
      g2l16(s_ + (sr_ * 58 + xc_) * 256 +                                      \
                (((sl_ & 8) | ((sl_ & 7) ^ (xc_ & 7))) << 4),                  \
            Astrip + idx_ * 16);                                               \
    }                                                                          \
  }

#define LOADB(d0, d1, d2, d3, uu)                                              \
  {                                                                            \
    const char* p_ = wtb + (unsigned)(uu) * 16384u;                            \
    d0 = *(const bf16x8_t*)(p_);          /* nj0 kseg0 */                      \
    d1 = *(const bf16x8_t*)(p_ + 1024);   /* nj0 kseg1 */                      \
    d2 = *(const bf16x8_t*)(p_ + 2048);   /* nj1 kseg0 */                      \
    d3 = *(const bf16x8_t*)(p_ + 3072);   /* nj1 kseg1 */                      \
  }

  // A frag reads: (mi, kseg) x (hi, lo); slot = cc*4+kseg*2+(l>>5) ^ (px&7)
#define READA(cc_, tyo_)                                                       \
  {                                                                            \
    _Pragma("unroll")                                                          \
    for (int mi = 0; mi < 2; ++mi) {                                           \
      int px_ = pxb[mi] + (tyo_);                                              \
      _Pragma("unroll")                                                        \
      for (int ks = 0; ks < 2; ++ks) {                                         \
        int slot_ = (((cc_) << 2) + (ks << 1) + (l >> 5)) ^ (px_ & 7);         \
        int base_ = (px_ << 8) + (slot_ << 4);                                 \
        ahi[mi][ks] = *(const bf16x8_t*)(Astrip + base_);                      \
        alo[mi][ks] = *(const bf16x8_t*)(Astrip + base_ + 128);                \
      }                                                                        \
    }                                                                          \
  }

#define MMA16(B0, B1, B2, B3)                                                  \
  __builtin_amdgcn_s_setprio(1);                                               \
  _Pragma("unroll")                                                            \
  for (int mi = 0; mi < 2; ++mi) {                                             \
    acc[mi][0] = __builtin_amdgcn_mfma_f32_32x32x16_bf16(ahi[mi][0], B0, acc[mi][0], 0, 0, 0); \
    acc[mi][1] = __builtin_amdgcn_mfma_f32_32x32x16_bf16(ahi[mi][0], B2, acc[mi][1], 0, 0, 0); \
    acc[mi][0] = __builtin_amdgcn_mfma_f32_32x32x16_bf16(ahi[mi][1], B1, acc[mi][0], 0, 0, 0); \
    acc[mi][1] = __builtin_amdgcn_mfma_f32_32x32x16_bf16(ahi[mi][1], B3, acc[mi][1], 0, 0, 0); \
    acc[mi][0] = __builtin_amdgcn_mfma_f32_32x32x16_bf16(alo[mi][0], B0, acc[mi][0], 0, 0, 0); \
    acc[mi][1] = __builtin_amdgcn_mfma_f32_32x32x16_bf16(alo[mi][0], B2, acc[mi][1], 0, 0, 0); \
    acc[mi][0] = __builtin_amdgcn_mfma_f32_32x32x16_bf16(alo[mi][1], B1, acc[mi][0], 0, 0, 0); \
    acc[mi][1] = __builtin_amdgcn_mfma_f32_32x32x16_bf16(alo[mi][1], B3, acc[mi][1], 0, 0, 0); \
  }                                                                            \
  __builtin_amdgcn_s_setprio(0);

#define QUANTIZE(gg, ss)                                                       \
  {                                                                            \
    float sw = ((gg) & 2) ? (((gg) & 1) ? w3s : w2s) : (((gg) & 1) ? w1s : w0s); \
    float sp = ((gg) & 2) ? (((gg) & 1) ? p3 : p2) : (((gg) & 1) ? p1 : p0);   \
    float sn = ((gg) & 2) ? (((gg) & 1) ? n3 : n2) : (((gg) & 1) ? n1 : n0);   \
    float sq = (ss) ? sn : sp;                                                 \
    float rs = sw / sq;                                                        \
    float sm = (ss) ? -sq : sq;                                                \
    _Pragma("unroll")                                                          \
    for (int mi = 0; mi < 2; ++mi)                                             \
      _Pragma("unroll")                                                        \
      for (int nj = 0; nj < 2; ++nj)                                           \
        _Pragma("unroll")                                                      \
        for (int e = 0; e < 16; ++e) {                                         \
          float v = acc[mi][nj][e] * rs;                                       \
          v = fminf(fmaxf(v, -128.f), 127.f);                                  \
          oacc[mi][nj][e] += sm * rintf(v);                                    \
          acc[mi][nj][e] = 0.f;                                                \
        }                                                                      \
  }

  bf16x8_t ahi[2][2], alo[2][2];
  bf16x8_t bA0, bA1, bA2, bA3, bB0, bB1, bB2, bB3;

  // ---- prologue: strip(0) [16] then B(0), B(1) [8] in flight
  STAGE_STRIP(0);
  MEMPIN;
  LOADB(bA0, bA1, bA2, bA3, 0);
  LOADB(bB0, bB1, bB2, bB3, 1);

  int tap = 0, sgn = 0, g = 0;
  for (int v = 0; v < 72; ++v) {
    const int ty = tap / 3;
    const int tyo = (ty << 6) + (tap - ty * 3);

    // ---- even unit u=2v (cc=0), consumes set A
    VMCNT4;                       // strip (if pending) + B(2v) landed
    if (tap == 0) { BAR; }        // group entry: strip published by all waves
    MEMPIN;
    READA(0, tyo);
    MMA16(bA0, bA1, bA2, bA3);
    MEMPIN;
    if (v < 71) { LOADB(bA0, bA1, bA2, bA3, 2 * v + 2); }

    // ---- odd unit u=2v+1 (cc=1), consumes set B
    if (v == 71) { VMCNT0; } else { VMCNT4; }
    MEMPIN;
    READA(1, tyo);
    MMA16(bB0, bB1, bB2, bB3);

    if (tap == 8) {
      QUANTIZE(g, sgn);
      if (sgn == 1 && v < 71) {
        BAR;                      // all waves' strip reads complete (lgkm'd)
        STAGE_STRIP(g + 1);       // republish before next B issue
      }
    }
    MEMPIN;
    if (v < 71) { LOADB(bB0, bB1, bB2, bB3, 2 * v + 3); }

    if (++tap == 9) { tap = 0; g += sgn; sgn ^= 1; }
  }

  // ---- store: C/D 32x32 layout col=l&31, row=(reg&3)+8*(reg>>2)+4*(l>>5)
  //      rows come in contiguous 4s -> f32x4 stores
#pragma unroll
  for (int nj = 0; nj < 2; ++nj) {
    int oc = (wv << 6) + nj * 32 + (l & 31);
    float* orow = out + ((size_t)(b * 256 + oc)) * 3136;
#pragma unroll
    for (int mi = 0; mi < 2; ++mi) {
#pragma unroll
      for (int q = 0; q < 4; ++q) {
        int m0 = (t << 6) + mi * 32 + q * 8 + ((l >> 5) << 2);
        f32x4_t vst;
        vst[0] = oacc[mi][nj][q * 4 + 0];
        vst[1] = oacc[mi][nj][q * 4 + 1];
        vst[2] = oacc[mi][nj][q * 4 + 2];
        vst[3] = oacc[mi][nj][q * 4 + 3];
        *(f32x4_t*)(orow + m0) = vst;
      }
    }
  }
#undef STAGE_STRIP
#undef LOADB
#undef READA
#undef MMA16
#undef QUANTIZE
}

// ---------------------------------------------------------------------------
// Fallback (ws too small): direct conv with inline weight quantization.
// ---------------------------------------------------------------------------
__global__ __launch_bounds__(256) void naive_conv(
    const float* __restrict__ x, const float* __restrict__ wgt,
    const float* __restrict__ wsc, const float* __restrict__ psp,
    const float* __restrict__ psn, float* __restrict__ out) {
  int idx = blockIdx.x * 256 + threadIdx.x;
  if (idx >= 12845056) return;
  int b = idx / 802816;
  int r = idx - b * 802816;
  int oc = r / 3136;
  int hw = r - oc * 3136;
  int h = hw / 56, w = hw - (hw / 56) * 56;
  float o = 0.f;
  for (int g = 0; g < 4; ++g) {
    float sw = wsc[g];
    float inv = 1.f / sw;
    float pp = 0.f, pn = 0.f;
    for (int tap = 0; tap < 9; ++tap) {
      int y = h + tap / 3 - 1, xx = w + tap % 3 - 1;
      if (y < 0 || y > 55 || xx < 0 || xx > 55) continue;
      const float* xr = x + (size_t)(b * 256 + g * 64) * 3136 + y * 56 + xx;
      const float* wrr = wgt + (size_t)oc * 2304 + (size_t)(g * 64) * 9 + tap;
      for (int c = 0; c < 64; ++c) {
        float xv = xr[(size_t)c * 3136];
        float rv = wrr[c * 9] * inv;
        pp += xv * rintf(fminf(fmaxf(rv, 0.f), 3.f));
        pn += xv * rintf(fminf(fmaxf(-rv, 0.f), 3.f));
      }
    }
    float sp = psp[g], sn = psn[g];
    o += rintf(fminf(fmaxf(pp * (sw / sp), -128.f), 127.f)) * sp;
    o -= rintf(fminf(fmaxf(pn * (sw / sn), -128.f), 127.f)) * sn;
  }
  out[idx] = o;
}

extern "C" void kernel_launch(void* const* d_in, const int* in_sizes, int n_in,
                              void* d_out, int out_size, void* d_ws, size_t ws_size,
                              hipStream_t stream) {
  const float* x = (const float*)d_in[0];
  const float* wgt = (const float*)d_in[1];
  const float* wsc = (const float*)d_in[2];
  const float* psp = (const float*)d_in[3];
  const float* psn = (const float*)d_in[4];
  float* out = (float*)d_out;

  if (ws_size >= (size_t)XP_BYTES + (size_t)WT_BYTES) {
    unsigned short* xpw = (unsigned short*)d_ws;
    unsigned short* wtw = (unsigned short*)((char*)d_ws + XP_BYTES);
    prep_x<<<3584, 256, 0, stream>>>(x, (__hip_bfloat16*)xpw);
    prep_w<<<576, 256, 0, stream>>>(wgt, wsc, wtw);
    conv_mfma<<<784, 256, 0, stream>>>(xpw, wtw, wsc, psp, psn, out);
  } else {
    naive_conv<<<(12845056 + 255) / 256, 256, 0, stream>>>(x, wgt, wsc, psp, psn, out);
  }
}

// Round 13
// 240.091 us; speedup vs baseline: 10.7410x; 1.0977x over previous
//
#include <hip/hip_runtime.h>
#include <hip/hip_bf16.h>

typedef __attribute__((ext_vector_type(8))) short bf16x8_t;
typedef __attribute__((ext_vector_type(4))) float f32x4_t;
typedef __attribute__((ext_vector_type(4))) unsigned int u32x4_t;

#define XP_BYTES 55115776u   // 4*16*58*58*128*2
#define WT_BYTES 2359296u    // 144 units * 256 oc * 32 k * 2B (frag-native)

typedef __attribute__((address_space(1))) const unsigned int ga_u32_t;
typedef __attribute__((address_space(3))) unsigned int lds_u32_t;

__device__ __forceinline__ void g2l16(const void* g, void* l) {
  __builtin_amdgcn_global_load_lds((ga_u32_t*)g, (lds_u32_t*)l, 16, 0, 0);
}

// ---------------------------------------------------------------------------
// prep_x: x (16,256,56,56) f32 -> xp (4,16,58,58,128) bf16, inner = hl*64+c.
// Writes its own zero borders (rows 0/57, cols 0/57) -> no xp memset needed.
// ---------------------------------------------------------------------------
__global__ __launch_bounds__(256) void prep_x(const float* __restrict__ x,
                                              __hip_bfloat16* __restrict__ xp) {
  __shared__ float ls[64 * 57];
  int blk = blockIdx.x;            // (g, b, h) : 4*16*56 = 3584
  int g = blk / 896;
  int r = blk - g * 896;
  int b = r / 56;
  int h = r - b * 56;
  int tid = threadIdx.x;
  const float* src = x + (size_t)(b * 256 + g * 64) * 3136 + h * 56;
  for (int i = tid; i < 64 * 56; i += 256) {
    int c = i / 56, w = i - c * 56;
    ls[c * 57 + w] = src[(size_t)c * 3136 + w];
  }
  __syncthreads();
  __hip_bfloat16* gbbase = xp + (size_t)(g * 16 + b) * 58 * 58 * 128;
  __hip_bfloat16* dst = gbbase + ((size_t)(h + 1) * 58 + 1) * 128;
  int wp = tid >> 7;
  int inner = tid & 127;
  int hl = inner >> 6, c = inner & 63;
  for (int w0 = 0; w0 < 56; w0 += 2) {
    int w = w0 + wp;
    float v = ls[c * 57 + w];
    __hip_bfloat16 hi = __float2bfloat16(v);
    __hip_bfloat16 val = hl ? __float2bfloat16(v - __bfloat162float(hi)) : hi;
    dst[(size_t)w * 128 + inner] = val;
  }
  __hip_bfloat16 z = __float2bfloat16(0.0f);
  {
    __hip_bfloat16* rowp = gbbase + (size_t)(h + 1) * 58 * 128;
    if (tid < 128) rowp[inner] = z;              // col 0
    else           rowp[57 * 128 + inner] = z;   // col 57
  }
  if (h == 0) {
    for (int i = tid; i < 58 * 128; i += 256) gbbase[i] = z;    // row 0
  }
  if (h == 55) {
    __hip_bfloat16* r57 = gbbase + (size_t)57 * 58 * 128;
    for (int i = tid; i < 58 * 128; i += 256) r57[i] = z;       // row 57
  }
}

// ---------------------------------------------------------------------------
// prep_w: weight (256,256,3,3) f32 -> FRAG-NATIVE layout (16x16x32 MFMA):
//   wtf[u][wq 0..3][ni 0..3][lane 0..63][8 bf16]
// u = g*36 + sgn*18 + tap*2 + cc; lane's 16B = its MFMA B-operand fragment:
// oc = wq*64 + ni*16 + (l&15), k = (l>>4)*8 + e, channel c = cc*32 + k.
// ---------------------------------------------------------------------------
__global__ __launch_bounds__(256) void prep_w(const float* __restrict__ wgt,
                                              const float* __restrict__ wsc,
                                              unsigned short* __restrict__ wtf) {
  int idx = blockIdx.x * 256 + threadIdx.x;   // 147456 = 144*4*4*64
  if (idx >= 147456) return;
  int l = idx & 63;
  int ni = (idx >> 6) & 3;
  int wq = (idx >> 8) & 3;
  int u = idx >> 10;                          // 0..143
  int g = u / 36;
  int r36 = u - g * 36;
  int sgn = (r36 >= 18) ? 1 : 0;
  int r18 = r36 - sgn * 18;
  int tap = r18 >> 1, cc = r18 & 1;
  int oc = wq * 64 + ni * 16 + (l & 15);
  float inv = 1.f / wsc[g];
  unsigned short pk[8];
#pragma unroll
  for (int e = 0; e < 8; ++e) {
    int c = cc * 32 + ((l >> 4) << 3) + e;
    float w = wgt[(size_t)oc * 2304 + (g * 64 + c) * 9 + tap] * inv;
    if (sgn) w = -w;
    float q = rintf(fminf(fmaxf(w, 0.f), 3.f));
    union { __hip_bfloat16 h; unsigned short s; } cv;
    cv.h = __float2bfloat16(q);
    pk[e] = cv.s;
  }
  u32x4_t v;
  v[0] = (unsigned)pk[0] | ((unsigned)pk[1] << 16);
  v[1] = (unsigned)pk[2] | ((unsigned)pk[3] << 16);
  v[2] = (unsigned)pk[4] | ((unsigned)pk[5] << 16);
  v[3] = (unsigned)pk[6] | ((unsigned)pk[7] << 16);
  *(u32x4_t*)(wtf + (size_t)idx * 8) = v;
}

// ---------------------------------------------------------------------------
// Main conv — R7 skeleton (measured 241us) + two-sweep MFMA reorder.
// Grid 784 = 16 b x 49 aligned 64-px tiles. BM=64 px, BN=256 oc. 256 thr =
// 4 waves (N quarters), wave tile 64x64, 2 blocks/CU (LDS 64KB).
// A: 4-row strip (64KB LDS), staged once per group; taps = LDS offsets;
//    conflict-free XOR swizzle. Barriers only at group boundaries.
// B: frag-native global->register, 2-deep set pipeline, counted VMCNT4.
// MMA32: sweep all 16 ahi-MFMAs (16 independent acc streams) then all 16
// alo-MFMAs — chain gap 0 -> 15 instructions (dependent-pair stall fix).
// ---------------------------------------------------------------------------
#define MEMPIN asm volatile("" ::: "memory")
#define BAR __builtin_amdgcn_s_barrier()
#define VMCNT4 asm volatile("s_waitcnt vmcnt(4)" ::: "memory")
#define VMCNT0 asm volatile("s_waitcnt vmcnt(0)" ::: "memory")

__global__ __launch_bounds__(256, 2) void conv_mfma(
    const unsigned short* __restrict__ xp, const unsigned short* __restrict__ wtf,
    const float* __restrict__ wsc, const float* __restrict__ psp,
    const float* __restrict__ psn, float* __restrict__ out) {
  __shared__ char Astrip[65536];               // 4 rows x 64 px x 256B

  const int bid = blockIdx.x;
  const int wg = (bid & 7) * 98 + (bid >> 3);  // bijective XCD swizzle (784=8*98)
  const int b = wg / 49;
  const int t = wg - b * 49;
  const int r0 = (t << 6) / 56;                // top padded xp-row of strip

  const int tid = threadIdx.x;
  const int wv = tid >> 6;                     // N quarter 0..3
  const int l = tid & 63;

  // ---- A frag pixel bases (strip-relative, 64-px row stride)
  int pxb[4];
#pragma unroll
  for (int mi = 0; mi < 4; ++mi) {
    int m = (t << 6) + mi * 16 + (l & 15);
    int rv = m / 56, w = m - rv * 56;
    pxb[mi] = ((rv - r0) << 6) + w;
  }

  // ---- scalars preloaded
  float w0s = wsc[0], w1s = wsc[1], w2s = wsc[2], w3s = wsc[3];
  float p0 = psp[0], p1 = psp[1], p2 = psp[2], p3 = psp[3];
  float n0 = psn[0], n1 = psn[1], n2 = psn[2], n3 = psn[3];

  f32x4_t acc[4][4], oacc[4][4];
  const f32x4_t fz = {0.f, 0.f, 0.f, 0.f};
#pragma unroll
  for (int i = 0; i < 4; ++i)
#pragma unroll
    for (int j = 0; j < 4; ++j) { acc[i][j] = fz; oacc[i][j] = fz; }

  const char* xg = (const char*)xp;
  const char* wtb = (const char*)wtf + (wv << 12) + (l << 4);  // per-lane B base
  const unsigned a_gbbase = (unsigned)((b * 3364 + r0 * 58) * 256);

  // stage the 64KB strip for group gg (16 loads/thread)
#define STAGE_STRIP(gg)                                                        \
  {                                                                            \
    const char* s_ = xg + (unsigned)(gg)*13778944u + a_gbbase;                 \
    _Pragma("unroll")                                                          \
    for (int k_ = 0; k_ < 16; ++k_) {                                          \
      int idx_ = tid + (k_ << 8);                                              \
      int px_ = idx_ >> 4, sl_ = idx_ & 15;                                    \
      int sr_ = px_ >> 6, xc_ = px_ & 63;                                      \
      g2l16(s_ + (sr_ * 58 + xc_) * 256 +                                      \
                (((sl_ & 8) | ((sl_ & 7) ^ (xc_ & 7))) << 4),                  \
            Astrip + idx_ * 16);                                               \
    }                                                                          \
  }

#define LOADB(d0, d1, d2, d3, uu)                                              \
  {                                                                            \
    const char* p_ = wtb + (unsigned)(uu) * 16384u;                            \
    d0 = *(const bf16x8_t*)(p_);                                               \
    d1 = *(const bf16x8_t*)(p_ + 1024);                                        \
    d2 = *(const bf16x8_t*)(p_ + 2048);                                        \
    d3 = *(const bf16x8_t*)(p_ + 3072);                                        \
  }

  // A frag reads for k-half cc_ at tap offset tyo (8 ds_read_b128)
#define READA(cc_, tyo_)                                                       \
  {                                                                            \
    const int kj_ = ((cc_) << 2) + (l >> 4);                                   \
    _Pragma("unroll")                                                          \
    for (int mi = 0; mi < 4; ++mi) {                                           \
      int px_ = pxb[mi] + (tyo_);                                              \
      int base_ = (px_ << 8) + ((kj_ ^ (px_ & 7)) << 4);                       \
      ahi[mi] = *(const bf16x8_t*)(Astrip + base_);                            \
      alo[mi] = *(const bf16x8_t*)(Astrip + base_ + 128);                      \
    }                                                                          \
  }

  // two sweeps: 16 independent ahi-MFMAs, then 16 alo-MFMAs (chain gap 15)
#define MMA32(B0, B1, B2, B3)                                                  \
  __builtin_amdgcn_s_setprio(1);                                               \
  _Pragma("unroll")                                                            \
  for (int mi = 0; mi < 4; ++mi) {                                             \
    acc[mi][0] = __builtin_amdgcn_mfma_f32_16x16x32_bf16(ahi[mi], B0, acc[mi][0], 0, 0, 0); \
    acc[mi][1] = __builtin_amdgcn_mfma_f32_16x16x32_bf16(ahi[mi], B1, acc[mi][1], 0, 0, 0); \
    acc[mi][2] = __builtin_amdgcn_mfma_f32_16x16x32_bf16(ahi[mi], B2, acc[mi][2], 0, 0, 0); \
    acc[mi][3] = __builtin_amdgcn_mfma_f32_16x16x32_bf16(ahi[mi], B3, acc[mi][3], 0, 0, 0); \
  }                                                                            \
  _Pragma("unroll")                                                            \
  for (int mi = 0; mi < 4; ++mi) {                                             \
    acc[mi][0] = __builtin_amdgcn_mfma_f32_16x16x32_bf16(alo[mi], B0, acc[mi][0], 0, 0, 0); \
    acc[mi][1] = __builtin_amdgcn_mfma_f32_16x16x32_bf16(alo[mi], B1, acc[mi][1], 0, 0, 0); \
    acc[mi][2] = __builtin_amdgcn_mfma_f32_16x16x32_bf16(alo[mi], B2, acc[mi][2], 0, 0, 0); \
    acc[mi][3] = __builtin_amdgcn_mfma_f32_16x16x32_bf16(alo[mi], B3, acc[mi][3], 0, 0, 0); \
  }                                                                            \
  __builtin_amdgcn_s_setprio(0);

#define QUANTIZE(gg, ss)                                                       \
  {                                                                            \
    float sw = ((gg) & 2) ? (((gg) & 1) ? w3s : w2s) : (((gg) & 1) ? w1s : w0s); \
    float sp = ((gg) & 2) ? (((gg) & 1) ? p3 : p2) : (((gg) & 1) ? p1 : p0);   \
    float sn = ((gg) & 2) ? (((gg) & 1) ? n3 : n2) : (((gg) & 1) ? n1 : n0);   \
    float sq = (ss) ? sn : sp;                                                 \
    float rs = sw / sq;                                                        \
    float sm = (ss) ? -sq : sq;                                                \
    _Pragma("unroll")                                                          \
    for (int mi = 0; mi < 4; ++mi)                                             \
      _Pragma("unroll")                                                        \
      for (int ni = 0; ni < 4; ++ni)                                           \
        _Pragma("unroll")                                                      \
        for (int j = 0; j < 4; ++j) {                                          \
          float v = acc[mi][ni][j] * rs;                                       \
          v = fminf(fmaxf(v, -128.f), 127.f);                                  \
          oacc[mi][ni][j] += sm * rintf(v);                                    \
          acc[mi][ni][j] = 0.f;                                                \
        }                                                                      \
  }

  bf16x8_t ahi[4], alo[4];
  bf16x8_t bA0, bA1, bA2, bA3, bB0, bB1, bB2, bB3;

  // ---- prologue: strip(0) [16] then B(0), B(1) [8] in flight
  STAGE_STRIP(0);
  MEMPIN;
  LOADB(bA0, bA1, bA2, bA3, 0);
  LOADB(bB0, bB1, bB2, bB3, 1);

  int tap = 0, sgn = 0, g = 0;
  for (int v = 0; v < 72; ++v) {
    const int ty = tap / 3;
    const int tyo = (ty << 6) + (tap - ty * 3);

    // ---- even unit u=2v (cc=0), consumes set A
    VMCNT4;                       // strip (if pending) + B(2v) landed
    if (tap == 0) { BAR; }        // group entry: strip published by all waves
    MEMPIN;
    READA(0, tyo);
    MMA32(bA0, bA1, bA2, bA3);
    MEMPIN;
    if (v < 71) { LOADB(bA0, bA1, bA2, bA3, 2 * v + 2); }

    // ---- odd unit u=2v+1 (cc=1), consumes set B
    if (v == 71) { VMCNT0; } else { VMCNT4; }
    MEMPIN;
    READA(1, tyo);
    MMA32(bB0, bB1, bB2, bB3);

    if (tap == 8) {
      QUANTIZE(g, sgn);
      if (sgn == 1 && v < 71) {
        BAR;                      // all waves done reading strip(g)
        STAGE_STRIP(g + 1);       // republish before next B issue
      }
    }
    MEMPIN;
    if (v < 71) { LOADB(bB0, bB1, bB2, bB3, 2 * v + 3); }

    if (++tap == 9) { tap = 0; g += sgn; sgn ^= 1; }
  }

  // ---- store (64-px tiles are image-row-aligned: no masking needed)
#pragma unroll
  for (int ni = 0; ni < 4; ++ni) {
    int oc = (wv << 6) + ni * 16 + (l & 15);
    float* orow = out + ((size_t)(b * 256 + oc)) * 3136;
#pragma unroll
    for (int mi = 0; mi < 4; ++mi) {
      int m0 = (t << 6) + mi * 16 + ((l >> 4) << 2);
#pragma unroll
      for (int j = 0; j < 4; ++j) {
        orow[m0 + j] = oacc[mi][ni][j];
      }
    }
  }
#undef STAGE_STRIP
#undef LOADB
#undef READA
#undef MMA32
#undef QUANTIZE
}

// ---------------------------------------------------------------------------
// Fallback (ws too small): direct conv with inline weight quantization.
// ---------------------------------------------------------------------------
__global__ __launch_bounds__(256) void naive_conv(
    const float* __restrict__ x, const float* __restrict__ wgt,
    const float* __restrict__ wsc, const float* __restrict__ psp,
    const float* __restrict__ psn, float* __restrict__ out) {
  int idx = blockIdx.x * 256 + threadIdx.x;
  if (idx >= 12845056) return;
  int b = idx / 802816;
  int r = idx - b * 802816;
  int oc = r / 3136;
  int hw = r - oc * 3136;
  int h = hw / 56, w = hw - (hw / 56) * 56;
  float o = 0.f;
  for (int g = 0; g < 4; ++g) {
    float sw = wsc[g];
    float inv = 1.f / sw;
    float pp = 0.f, pn = 0.f;
    for (int tap = 0; tap < 9; ++tap) {
      int y = h + tap / 3 - 1, xx = w + tap % 3 - 1;
      if (y < 0 || y > 55 || xx < 0 || xx > 55) continue;
      const float* xr = x + (size_t)(b * 256 + g * 64) * 3136 + y * 56 + xx;
      const float* wrr = wgt + (size_t)oc * 2304 + (size_t)(g * 64) * 9 + tap;
      for (int c = 0; c < 64; ++c) {
        float xv = xr[(size_t)c * 3136];
        float rv = wrr[c * 9] * inv;
        pp += xv * rintf(fminf(fmaxf(rv, 0.f), 3.f));
        pn += xv * rintf(fminf(fmaxf(-rv, 0.f), 3.f));
      }
    }
    float sp = psp[g], sn = psn[g];
    o += rintf(fminf(fmaxf(pp * (sw / sp), -128.f), 127.f)) * sp;
    o -= rintf(fminf(fmaxf(pn * (sw / sn), -128.f), 127.f)) * sn;
  }
  out[idx] = o;
}

extern "C" void kernel_launch(void* const* d_in, const int* in_sizes, int n_in,
                              void* d_out, int out_size, void* d_ws, size_t ws_size,
                              hipStream_t stream) {
  const float* x = (const float*)d_in[0];
  const float* wgt = (const float*)d_in[1];
  const float* wsc = (const float*)d_in[2];
  const float* psp = (const float*)d_in[3];
  const float* psn = (const float*)d_in[4];
  float* out = (float*)d_out;

  if (ws_size >= (size_t)XP_BYTES + (size_t)WT_BYTES) {
    unsigned short* xpw = (unsigned short*)d_ws;
    unsigned short* wtw = (unsigned short*)((char*)d_ws + XP_BYTES);
    prep_x<<<3584, 256, 0, stream>>>(x, (__hip_bfloat16*)xpw);
    prep_w<<<576, 256, 0, stream>>>(wgt, wsc, wtw);
    conv_mfma<<<784, 256, 0, stream>>>(xpw, wtw, wsc, psp, psn, out);
  } else {
    naive_conv<<<(12845056 + 255) / 256, 256, 0, stream>>>(x, wgt, wsc, psp, psn, out);
  }
}